// Round 3
// baseline (766.921 us; speedup 1.0000x reference)
//
#include <hip/hip_runtime.h>

// out[b][pc] = sum_n x[b][n] * kern[n][pc];  B=32, N=16384, PC=8192.
// HBM-bound on the 537 MB kern stream (~270 MB from HBM after L3 retention).
//
// R3: float4-kern/thread x full-B(32) accs (AGPRs). x read from LDS via
// wave-uniform ds_read_b128 broadcasts (8/j). KSPLIT=96 -> grid 768 = 3
// blocks/CU = 3 waves/SIMD. Triple-buffered kv prefetch so compiler emits
// vmcnt(N>0) instead of draining per unroll group. No atomics: partials to
// d_ws, second reduce kernel sums 96 chunks -> d_out (no memset needed).

#define B_DIM  32
#define NVOX   16384
#define PC_DIM 8192
#define PC4    (PC_DIM / 4)      // 2048 float4 columns
#define KSPLIT 96
#define CHUNK  172               // ceil(16384/96); last chunks shorter
#define TPB    256
#define PART_F4_PER_CHUNK (B_DIM * PC4)   // 65536 float4 per k-chunk

// --- transpose x (B, N) -> xt (N, B), coalesced both sides via LDS ---
__global__ __launch_bounds__(TPB)
void lp_transpose(const float* __restrict__ x, float* __restrict__ xt) {
    __shared__ float s[B_DIM][TPB + 1];
    const int t  = threadIdx.x;
    const int n0 = blockIdx.x * TPB;
#pragma unroll
    for (int b = 0; b < B_DIM; ++b)
        s[b][t] = x[(size_t)b * NVOX + n0 + t];
    __syncthreads();
#pragma unroll
    for (int g = 0; g < B_DIM; ++g) {
        const int flat = g * TPB + t;
        const int i = flat >> 5;
        const int b = flat & 31;
        xt[(size_t)(n0 + i) * B_DIM + b] = s[b][i];
    }
}

// --- main GEMM: partials to ws ---
__global__ __launch_bounds__(TPB, 3)
void lp_gemm(const float* __restrict__ kern, const float* __restrict__ xt,
             float* __restrict__ part) {
    __shared__ float4 xs4[CHUNK * (B_DIM / 4)];      // xs[n][b], 22 KB

    const int t   = threadIdx.x;
    const int c4  = blockIdx.x * TPB + t;            // float4 pc column
    const int kc  = blockIdx.y;                      // k-chunk id
    const int n0  = kc * CHUNK;
    const int len = min(CHUNK, NVOX - n0);           // >= 44

    // stage xt[n0 .. n0+len) x 32  ->  LDS (coalesced, conflict-free)
    const float4* __restrict__ xt4 = (const float4*)xt + (size_t)n0 * (B_DIM / 4);
    const int nf4 = len * (B_DIM / 4);               // multiple of 8
    for (int i = t; i < nf4; i += TPB)
        xs4[i] = xt4[i];
    __syncthreads();

    float4 acc[B_DIM];
#pragma unroll
    for (int b = 0; b < B_DIM; ++b) acc[b] = make_float4(0.f, 0.f, 0.f, 0.f);

    const float4* __restrict__ kp = (const float4*)kern + (size_t)n0 * PC4 + c4;

    // triple-buffered kv stream: load j+2 while computing j
    float4 kv0 = kp[0];
    float4 kv1 = kp[PC4];
    for (int j = 0; j < len; ++j) {
        const int jn = (j + 2 < len) ? (j + 2) : (len - 1);   // uniform clamp
        float4 kv2 = kp[(size_t)jn * PC4];
        const float4* xrow = &xs4[j * (B_DIM / 4)];
#pragma unroll
        for (int b8 = 0; b8 < 8; ++b8) {
            float4 xv = xrow[b8];                    // ds_read_b128 broadcast
            const int bb = b8 * 4;
            acc[bb+0].x += xv.x * kv0.x; acc[bb+0].y += xv.x * kv0.y;
            acc[bb+0].z += xv.x * kv0.z; acc[bb+0].w += xv.x * kv0.w;
            acc[bb+1].x += xv.y * kv0.x; acc[bb+1].y += xv.y * kv0.y;
            acc[bb+1].z += xv.y * kv0.z; acc[bb+1].w += xv.y * kv0.w;
            acc[bb+2].x += xv.z * kv0.x; acc[bb+2].y += xv.z * kv0.y;
            acc[bb+2].z += xv.z * kv0.z; acc[bb+2].w += xv.z * kv0.w;
            acc[bb+3].x += xv.w * kv0.x; acc[bb+3].y += xv.w * kv0.y;
            acc[bb+3].z += xv.w * kv0.z; acc[bb+3].w += xv.w * kv0.w;
        }
        kv0 = kv1; kv1 = kv2;
    }

    // partial[kc][b][pc] — coalesced float4 stores, no RMW
    float4* __restrict__ p4 = (float4*)part + (size_t)kc * PART_F4_PER_CHUNK + c4;
#pragma unroll
    for (int b = 0; b < B_DIM; ++b)
        p4[(size_t)b * PC4] = acc[b];
}

// --- reduce 96 partial chunks -> out ---
__global__ __launch_bounds__(TPB)
void lp_reduce(const float* __restrict__ part, float* __restrict__ out) {
    const int i = blockIdx.x * TPB + threadIdx.x;    // [0, 65536) float4 index
    const float4* __restrict__ p4 = (const float4*)part;
    float4 s = make_float4(0.f, 0.f, 0.f, 0.f);
#pragma unroll 8
    for (int kc = 0; kc < KSPLIT; ++kc) {
        float4 v = p4[(size_t)kc * PART_F4_PER_CHUNK + i];
        s.x += v.x; s.y += v.y; s.z += v.z; s.w += v.w;
    }
    ((float4*)out)[i] = s;
}

extern "C" void kernel_launch(void* const* d_in, const int* in_sizes, int n_in,
                              void* d_out, int out_size, void* d_ws, size_t ws_size,
                              hipStream_t stream) {
    const float* x    = (const float*)d_in[0];   // (32, 16384)
    const float* kern = (const float*)d_in[1];   // (16384, 8192)
    float* out = (float*)d_out;                  // (32, 8192)

    float* xt   = (float*)d_ws;                                  // 2 MB
    float* part = (float*)((char*)d_ws + (size_t)2 * 1024 * 1024); // 96 MB

    lp_transpose<<<NVOX / TPB, TPB, 0, stream>>>(x, xt);

    dim3 grid(PC4 / TPB, KSPLIT);                 // (8, 96) = 768 blocks
    lp_gemm<<<grid, TPB, 0, stream>>>(kern, xt, part);

    lp_reduce<<<(B_DIM * PC4) / TPB, TPB, 0, stream>>>(part, out);
}

// Round 4
// 702.548 us; speedup vs baseline: 1.0916x; 1.0916x over previous
//
#include <hip/hip_runtime.h>

// out[b][pc] = sum_n x[b][n] * kern[n][pc];  B=32, N=16384, PC=8192.
// HBM-bound on the 537 MB kern stream.
//
// R4: float2-kern/thread x 32 batch accs (64 VGPR accs -> 4 waves/SIMD).
// Grid (16,64) = 1024 blocks = 4 blocks/CU: exactly resident, one round,
// no tail imbalance. CHUNK=256 compile-time; kv prefetch ring depth 4
// (main trip 252 = 4x63, ring index static under unroll-4). x broadcast
// from LDS via ds_read_b128 (8/j). Partials to ws + separate reduce.

#define B_DIM  32
#define NVOX   16384
#define PC_DIM 8192
#define PC2    (PC_DIM / 2)      // 4096 float2 columns
#define KSPLIT 64
#define CHUNK  256               // NVOX / KSPLIT, exact
#define TPB    256
#define PART_F4_PER_CHUNK (B_DIM * PC_DIM / 4)   // 65536 float4 per k-chunk

// --- transpose x (B, N) -> xt (N, B), coalesced both sides via LDS ---
__global__ __launch_bounds__(TPB)
void lp_transpose(const float* __restrict__ x, float* __restrict__ xt) {
    __shared__ float s[B_DIM][TPB + 1];
    const int t  = threadIdx.x;
    const int n0 = blockIdx.x * TPB;
#pragma unroll
    for (int b = 0; b < B_DIM; ++b)
        s[b][t] = x[(size_t)b * NVOX + n0 + t];
    __syncthreads();
#pragma unroll
    for (int g = 0; g < B_DIM; ++g) {
        const int flat = g * TPB + t;
        const int i = flat >> 5;
        const int b = flat & 31;
        xt[(size_t)(n0 + i) * B_DIM + b] = s[b][i];
    }
}

// --- main GEMM: partials to ws ---
__global__ __launch_bounds__(TPB, 4)
void lp_gemm(const float* __restrict__ kern, const float* __restrict__ xt,
             float* __restrict__ part) {
    __shared__ float4 xs4[CHUNK * (B_DIM / 4)];      // xs[n][b], 32 KB

    const int t  = threadIdx.x;
    const int c2 = blockIdx.x * TPB + t;             // float2 pc column [0,4096)
    const int kc = blockIdx.y;                       // k-chunk id [0,64)
    const int n0 = kc * CHUNK;

    // stage xt[n0 .. n0+256) x 32 -> LDS (coalesced float4, conflict-free)
    const float4* __restrict__ xt4 = (const float4*)xt + (size_t)n0 * (B_DIM / 4);
#pragma unroll
    for (int i = 0; i < CHUNK * (B_DIM / 4) / TPB; ++i)
        xs4[i * TPB + t] = xt4[i * TPB + t];
    __syncthreads();

    float2 acc[B_DIM];
#pragma unroll
    for (int b = 0; b < B_DIM; ++b) acc[b] = make_float2(0.f, 0.f);

    const float2* __restrict__ kp = (const float2*)kern + (size_t)n0 * PC2 + c2;

    // prefetch ring, depth 4
    float2 ring[4];
#pragma unroll
    for (int j = 0; j < 4; ++j)
        ring[j] = kp[(size_t)j * PC2];

#define LP_BODY(J_EXPR, RING_SLOT)                                         \
    {                                                                      \
        const int jj = (J_EXPR);                                           \
        const float2 kv = ring[RING_SLOT];                                 \
        const float4* xrow = &xs4[jj * (B_DIM / 4)];                       \
        _Pragma("unroll")                                                  \
        for (int b8 = 0; b8 < 8; ++b8) {                                   \
            const float4 xv = xrow[b8];  /* ds_read_b128 broadcast */      \
            const int bb = b8 * 4;                                         \
            acc[bb+0].x = fmaf(xv.x, kv.x, acc[bb+0].x);                   \
            acc[bb+0].y = fmaf(xv.x, kv.y, acc[bb+0].y);                   \
            acc[bb+1].x = fmaf(xv.y, kv.x, acc[bb+1].x);                   \
            acc[bb+1].y = fmaf(xv.y, kv.y, acc[bb+1].y);                   \
            acc[bb+2].x = fmaf(xv.z, kv.x, acc[bb+2].x);                   \
            acc[bb+2].y = fmaf(xv.z, kv.y, acc[bb+2].y);                   \
            acc[bb+3].x = fmaf(xv.w, kv.x, acc[bb+3].x);                   \
            acc[bb+3].y = fmaf(xv.w, kv.y, acc[bb+3].y);                   \
        }                                                                  \
    }

    // main loop: compute j, refill slot with j+4.  trip 252 = 4 * 63.
#pragma unroll 4
    for (int j = 0; j < CHUNK - 4; ++j) {
        LP_BODY(j, j & 3);
        ring[j & 3] = kp[(size_t)(j + 4) * PC2];
    }
    // peeled tail: compute-only
#pragma unroll
    for (int j = CHUNK - 4; j < CHUNK; ++j) {
        LP_BODY(j, j & 3);
    }
#undef LP_BODY

    // partial[kc][b][pc] — coalesced float2 stores, no RMW
    float2* __restrict__ p2 = (float2*)part + (size_t)kc * (B_DIM * PC2) + c2;
#pragma unroll
    for (int b = 0; b < B_DIM; ++b)
        p2[(size_t)b * PC2] = acc[b];
}

// --- reduce 64 partial chunks -> out ---
__global__ __launch_bounds__(TPB)
void lp_reduce(const float* __restrict__ part, float* __restrict__ out) {
    const int i = blockIdx.x * TPB + threadIdx.x;    // [0, 65536) float4 index
    const float4* __restrict__ p4 = (const float4*)part;
    float4 s = make_float4(0.f, 0.f, 0.f, 0.f);
#pragma unroll 8
    for (int kc = 0; kc < KSPLIT; ++kc) {
        float4 v = p4[(size_t)kc * PART_F4_PER_CHUNK + i];
        s.x += v.x; s.y += v.y; s.z += v.z; s.w += v.w;
    }
    ((float4*)out)[i] = s;
}

extern "C" void kernel_launch(void* const* d_in, const int* in_sizes, int n_in,
                              void* d_out, int out_size, void* d_ws, size_t ws_size,
                              hipStream_t stream) {
    const float* x    = (const float*)d_in[0];   // (32, 16384)
    const float* kern = (const float*)d_in[1];   // (16384, 8192)
    float* out = (float*)d_out;                  // (32, 8192)

    float* xt   = (float*)d_ws;                                    // 2 MB
    float* part = (float*)((char*)d_ws + (size_t)2 * 1024 * 1024); // 64 MB

    lp_transpose<<<NVOX / TPB, TPB, 0, stream>>>(x, xt);

    dim3 grid(PC2 / TPB, KSPLIT);                 // (16, 64) = 1024 blocks
    lp_gemm<<<grid, TPB, 0, stream>>>(kern, xt, part);

    lp_reduce<<<(B_DIM * PC_DIM / 4) / TPB, TPB, 0, stream>>>(part, out);
}